// Round 1
// 3919.887 us; speedup vs baseline: 1.0129x; 1.0129x over previous
//
#include <hip/hip_runtime.h>
#include <hip/hip_bf16.h>

#define TT 512
#define BB 64
#define HH 128
#define GG 512   // 4*H
#define TBH (TT*BB*HH)
#define TBG (TT*BB*GG)
#define BH (BB*HH)

__device__ __forceinline__ float bflo(unsigned u) { return __uint_as_float(u << 16); }
__device__ __forceinline__ float bfhi(unsigned u) { return __uint_as_float(u & 0xffff0000u); }
__device__ __forceinline__ float ldf(const void* p, size_t i, int isbf) {
  return isbf ? __uint_as_float(((unsigned)((const unsigned short*)p)[i]) << 16)
              : ((const float*)p)[i];
}

template<int CTRL>
__device__ __forceinline__ float dpp_add(float v) {
  int r = __builtin_amdgcn_mov_dpp(__float_as_int(v), CTRL, 0xF, 0xF, true);
  return v + __int_as_float(r);
}

__device__ __forceinline__ float sigm(float x) {
  return __builtin_amdgcn_rcpf(1.f + __expf(-x));
}
__device__ __forceinline__ float tanh_f(float x) {
  return fmaf(2.f, __builtin_amdgcn_rcpf(1.f + __expf(-2.f * x)), -1.f);
}

__global__ __launch_bounds__(256) void k_detect(const unsigned* __restrict__ bits,
                                                unsigned* __restrict__ flag) {
  __shared__ int cnt;
  if (threadIdx.x == 0) cnt = 0;
  __syncthreads();
  int local = 0;
  for (int i = threadIdx.x; i < 1024; i += 256) {
    unsigned e = (bits[i] >> 7) & 0xff;
    if (e >= 118 && e <= 134) local++;
  }
  atomicAdd(&cnt, local);
  __syncthreads();
  if (threadIdx.x == 0) *flag = (cnt > 768) ? 1u : 0u;
}

__global__ __launch_bounds__(256) void k_embed(const int* __restrict__ idx,
                                               const void* __restrict__ emb,
                                               const unsigned* __restrict__ flag,
                                               float* __restrict__ x0) {
  int isbf = (int)*flag;
  int i = blockIdx.x * 256 + threadIdx.x;
  int h = i & (HH - 1);
  int tb = i >> 7;
  x0[i] = ldf(emb, (size_t)idx[tb] * HH + h, isbf);
}

// C[M,512] = A[M,K] @ W[512,K]^T + bias ; grid (M/64, 8)
__global__ __launch_bounds__(256) void k_proj(const float* __restrict__ A,
                                              const void* __restrict__ W, size_t w_off,
                                              const void* __restrict__ bias, size_t b_off,
                                              float* __restrict__ C, int K,
                                              const unsigned* __restrict__ flag) {
  int isbf = (int)*flag;
  __shared__ float As[16][68];
  __shared__ float Bs[16][68];
  int tid = threadIdx.x;
  int tx = tid & 15, ty = tid >> 4;
  int m_base = blockIdx.x * 64, n_base = blockIdx.y * 64;
  float acc[4][4] = {};
  int kk = tid & 15, rr = tid >> 4;
  for (int k0 = 0; k0 < K; k0 += 16) {
    #pragma unroll
    for (int r = 0; r < 4; r++) {
      As[kk][rr + 16*r] = A[(size_t)(m_base + rr + 16*r) * K + k0 + kk];
      Bs[kk][rr + 16*r] = ldf(W, w_off + (size_t)(n_base + rr + 16*r) * K + k0 + kk, isbf);
    }
    __syncthreads();
    #pragma unroll
    for (int k = 0; k < 16; k++) {
      float4 av = *(const float4*)(&As[k][ty*4]);
      float4 bv = *(const float4*)(&Bs[k][tx*4]);
      float a[4] = {av.x, av.y, av.z, av.w};
      float b[4] = {bv.x, bv.y, bv.z, bv.w};
      #pragma unroll
      for (int i = 0; i < 4; i++)
        #pragma unroll
        for (int j = 0; j < 4; j++)
          acc[i][j] += a[i] * b[j];
    }
    __syncthreads();
  }
  #pragma unroll
  for (int i = 0; i < 4; i++) {
    #pragma unroll
    for (int j = 0; j < 4; j++) {
      int n = n_base + tx*4 + j;
      C[(size_t)(m_base + ty*4 + i) * GG + n] = acc[i][j] + ldf(bias, b_off + n, isbf);
    }
  }
}

// One block per (batch, direction). 512 threads: t -> j=t>>2 (h column), q=t&3 (K quarter).
// Each thread computes all 4 gates of column j over its K-quarter; DPP quad butterflies
// complete the dots. Double-buffered h in LDS -> one barrier per step.
//
// Bank-conflict fix: thread q reads its quarter ROTATED by 8q elements (2 float4 chunks),
// and loads its W_hh register fragment pre-rotated by the same amount. Per read-instr u,
// the four q's now start at banks 4u + {0,8,16,24} (disjoint, 16 banks, broadcast within
// each 16-lane same-address group) instead of all landing on banks 4u..4u+3 (4-way).
__global__ __launch_bounds__(512, 2) void k_recur(
    const float* __restrict__ xg, size_t xg_dstride,
    const void* __restrict__ whh, size_t w_off, size_t w_dstride,
    float* __restrict__ hout, int hout_stride, int hout_doff,
    const float* __restrict__ res,
    float* __restrict__ hfin, float* __restrict__ cfin,
    int bidir, const unsigned* __restrict__ flag) {
  int isbf = (int)*flag;
  int d = blockIdx.x >> 6;
  int b = blockIdx.x & 63;
  int dir = (bidir == 2 || (bidir == 1 && d)) ? -1 : 1;
  xg += (size_t)d * xg_dstride;
  size_t woff = w_off + (size_t)d * w_dstride;
  int hcol = hout_doff * d;

  int t0 = threadIdx.x;
  int j = t0 >> 2, q = t0 & 3;

  // Load W_hh fragment: rows j + g*128, cols q*32 .. q*32+31, ROTATED left by 8q elements
  // so that register slot i holds W[row, q*32 + ((i + 8q) & 31)].  (128 f32 regs)
  float w[4][32];
  size_t wbase = woff + (size_t)j * HH + q * 32;
  if (isbf) {
    const uint4* wp = (const uint4*)whh;
    #pragma unroll
    for (int g = 0; g < 4; g++) {
      size_t b8 = (wbase + (size_t)g * 128 * HH) >> 3;
      #pragma unroll
      for (int u = 0; u < 4; u++) {
        uint4 v = wp[b8 + ((u + q) & 3)];          // rotate by q uint4-chunks (8 elems each)
        w[g][u*8+0] = bflo(v.x); w[g][u*8+1] = bfhi(v.x);
        w[g][u*8+2] = bflo(v.y); w[g][u*8+3] = bfhi(v.y);
        w[g][u*8+4] = bflo(v.z); w[g][u*8+5] = bfhi(v.z);
        w[g][u*8+6] = bflo(v.w); w[g][u*8+7] = bfhi(v.w);
      }
    }
  } else {
    const float4* wp = (const float4*)whh;
    #pragma unroll
    for (int g = 0; g < 4; g++) {
      size_t b4 = (wbase + (size_t)g * 128 * HH) >> 2;
      #pragma unroll
      for (int u = 0; u < 8; u++) {
        float4 v = wp[b4 + ((u + 2*q) & 7)];       // rotate by 2q float4-chunks (4 elems each)
        w[g][u*4+0] = v.x; w[g][u*4+1] = v.y; w[g][u*4+2] = v.z; w[g][u*4+3] = v.w;
      }
    }
  }

  __shared__ float h_lds[2][HH];
  if (t0 < HH) h_lds[0][t0] = 0.f;
  float c = 0.f;

  int tfirst = (dir > 0) ? 0 : (TT - 1);
  size_t rg0 = ((size_t)tfirst * BB + b) * GG;
  float xg_cur[4];
  #pragma unroll
  for (int g = 0; g < 4; g++) xg_cur[g] = xg[rg0 + g * HH + j];
  float res_cur = res ? res[((size_t)tfirst * BB + b) * HH + j] : 0.f;
  __syncthreads();

  const float* hc = h_lds[0];
  float* hn = h_lds[1];

  #pragma unroll 1
  for (int s = 0; s < TT; s++) {
    int t = (dir > 0) ? s : (TT - 1 - s);
    // prefetch next step's xg / residual (issued before the dot; latency hidden)
    float xg_nxt[4] = {0.f, 0.f, 0.f, 0.f};
    float res_nxt = 0.f;
    if (s + 1 < TT) {
      int tn = (dir > 0) ? (s + 1) : (TT - 2 - s);
      size_t rg = ((size_t)tn * BB + b) * GG;
      #pragma unroll
      for (int g = 0; g < 4; g++) xg_nxt[g] = xg[rg + g * HH + j];
      if (res) res_nxt = res[((size_t)tn * BB + b) * HH + j];
    }
    // quarter dot — read order rotated by 2q float4-chunks (matches pre-rotated w regs)
    float p0 = 0.f, p1 = 0.f, p2 = 0.f, p3 = 0.f;
    const float4* hq = (const float4*)(hc + (q << 5));
    #pragma unroll
    for (int u = 0; u < 8; u++) {
      float4 hv = hq[(u + 2*q) & 7];
      p0 = fmaf(w[0][u*4+0], hv.x, p0); p0 = fmaf(w[0][u*4+1], hv.y, p0);
      p0 = fmaf(w[0][u*4+2], hv.z, p0); p0 = fmaf(w[0][u*4+3], hv.w, p0);
      p1 = fmaf(w[1][u*4+0], hv.x, p1); p1 = fmaf(w[1][u*4+1], hv.y, p1);
      p1 = fmaf(w[1][u*4+2], hv.z, p1); p1 = fmaf(w[1][u*4+3], hv.w, p1);
      p2 = fmaf(w[2][u*4+0], hv.x, p2); p2 = fmaf(w[2][u*4+1], hv.y, p2);
      p2 = fmaf(w[2][u*4+2], hv.z, p2); p2 = fmaf(w[2][u*4+3], hv.w, p2);
      p3 = fmaf(w[3][u*4+0], hv.x, p3); p3 = fmaf(w[3][u*4+1], hv.y, p3);
      p3 = fmaf(w[3][u*4+2], hv.z, p3); p3 = fmaf(w[3][u*4+3], hv.w, p3);
    }
    // quad butterfly (VALU DPP, not DS): lanes q=0..3 all end with full dots
    p0 = dpp_add<0xB1>(p0); p0 = dpp_add<0x4E>(p0);
    p1 = dpp_add<0xB1>(p1); p1 = dpp_add<0x4E>(p1);
    p2 = dpp_add<0xB1>(p2); p2 = dpp_add<0x4E>(p2);
    p3 = dpp_add<0xB1>(p3); p3 = dpp_add<0x4E>(p3);

    float gi = p0 + xg_cur[0], gf = p1 + xg_cur[1];
    float gc = p2 + xg_cur[2], go = p3 + xg_cur[3];
    float si = sigm(gi), sf = sigm(gf), so = sigm(go);
    c = fmaf(sf, c, si * tanh_f(gc));
    float h = so * tanh_f(c);

    if (q == 0) {
      hn[j] = h;
      hout[((size_t)t * BB + b) * hout_stride + hcol + j] = h + res_cur;
      if (t == TT - 1) hfin[(size_t)(d * BB + b) * HH + j] = h;
    }
    #pragma unroll
    for (int g = 0; g < 4; g++) xg_cur[g] = xg_nxt[g];
    res_cur = res_nxt;
    __syncthreads();
    const float* tmp = hc; hc = hn; hn = (float*)tmp;
  }
  if (q == 0) cfin[(size_t)(d * BB + b) * HH + j] = c;
}

__global__ __launch_bounds__(256) void k_out(const float* __restrict__ x,
                                             const float* __restrict__ hfin,
                                             const float* __restrict__ cfin,
                                             void* __restrict__ out,
                                             const unsigned* __restrict__ flag) {
  int isbf = (int)*flag;
  int i = blockIdx.x * 256 + threadIdx.x;
  float v;
  if (i < TBH) v = x[i];
  else if (i < TBH + BH) v = hfin[i - TBH];
  else v = cfin[i - TBH - BH];
  if (isbf) ((__hip_bfloat16*)out)[i] = __float2bfloat16(v);
  else ((float*)out)[i] = v;
}

extern "C" void kernel_launch(void* const* d_in, const int* in_sizes, int n_in,
                              void* d_out, int out_size, void* d_ws, size_t ws_size,
                              hipStream_t stream) {
  const int* idx = (const int*)d_in[0];
  const void* emb   = d_in[1];
  const void* w_ih0 = d_in[2];
  const void* w_hh0 = d_in[3];
  const void* b0    = d_in[4];
  const void* w_ih1 = d_in[5];
  const void* w_hh1 = d_in[6];
  const void* b1    = d_in[7];
  const void* w_ihr = d_in[8];
  const void* w_hhr = d_in[9];
  const void* br    = d_in[10];

  float* ws   = (float*)d_ws;
  float* x0   = ws;                       // TBH
  float* xcat = ws + TBH;                 // 2*TBH  (xA = xcat, xB = xcat+TBH after L1)
  float* xg_f = ws + 3 * (size_t)TBH;     // TBG
  float* hfin = ws + 3 * (size_t)TBH + TBG;        // 2*BH
  float* cfin = hfin + 2 * BH;                     // 2*BH
  unsigned* flag = (unsigned*)(cfin + 2 * BH);
  float* xg_b = cfin + 2 * BH + 16384;    // TBG (merged path only)
  int merged = ws_size >= (size_t)(3 * (size_t)TBH + 2 * (size_t)TBG + 4 * BH + 16384 + 64) * 4;

  k_detect<<<1, 256, 0, stream>>>((const unsigned*)emb, flag);
  k_embed<<<TBH / 256, 256, 0, stream>>>(idx, emb, flag, x0);

  dim3 pg(512, 8);
  if (merged) {
    // L0 fwd+bwd concurrent: 128 blocks
    k_proj<<<pg, 256, 0, stream>>>(x0, w_ih0, 0, b0, 0, xg_f, HH, flag);
    k_proj<<<pg, 256, 0, stream>>>(x0, w_ih0, (size_t)GG * HH, b0, GG, xg_b, HH, flag);
    k_recur<<<128, 512, 0, stream>>>(xg_f, (size_t)(xg_b - xg_f), w_hh0, 0, (size_t)GG * HH,
                                     xcat, 2 * HH, HH, nullptr, hfin, cfin, 1, flag);
  } else {
    k_proj<<<pg, 256, 0, stream>>>(x0, w_ih0, 0, b0, 0, xg_f, HH, flag);
    k_recur<<<64, 512, 0, stream>>>(xg_f, 0, w_hh0, 0, 0,
                                    xcat, 2 * HH, 0, nullptr, hfin, cfin, 0, flag);
    k_proj<<<pg, 256, 0, stream>>>(x0, w_ih0, (size_t)GG * HH, b0, GG, xg_f, HH, flag);
    k_recur<<<64, 512, 0, stream>>>(xg_f, 0, w_hh0, (size_t)GG * HH, 0,
                                    xcat + HH, 2 * HH, 0, nullptr, hfin, cfin, 2, flag);
  }
  // layer 1: reads xcat [T,B,2H], writes xA (= xcat region, safe: proj done before recur)
  float* xA = xcat;
  float* xB = xcat + TBH;
  k_proj<<<pg, 256, 0, stream>>>(xcat, w_ih1, 0, b1, 0, xg_f, 2 * HH, flag);
  k_recur<<<64, 512, 0, stream>>>(xg_f, 0, w_hh1, 0, 0, xA, HH, 0, nullptr, hfin, cfin, 0, flag);
  // residual layers 2..7
  float* cur = xA;
  float* nxt = xB;
  for (int r = 0; r < 6; r++) {
    k_proj<<<pg, 256, 0, stream>>>(cur, w_ihr, (size_t)r * GG * HH, br, (size_t)r * GG, xg_f, HH, flag);
    k_recur<<<64, 512, 0, stream>>>(xg_f, 0, w_hhr, (size_t)r * GG * HH, 0,
                                    nxt, HH, 0, cur, hfin, cfin, 0, flag);
    float* t = cur; cur = nxt; nxt = t;
  }
  k_out<<<(TBH + 2 * BH) / 256, 256, 0, stream>>>(cur, hfin, cfin, d_out, flag);
}

// Round 2
// 3456.945 us; speedup vs baseline: 1.1486x; 1.1339x over previous
//
#include <hip/hip_runtime.h>
#include <hip/hip_bf16.h>

#define TT 512
#define BB 64
#define HH 128
#define GG 512   // 4*H
#define TBH (TT*BB*HH)
#define TBG (TT*BB*GG)
#define BH (BB*HH)
#define CH 64                 // wavefront chunk length (timesteps)
#define NCH (TT/CH)           // 8 chunks
#define CHGG (CH*BB*GG)       // floats per xg chunk slot
#define CHH (CH*BB*HH)        // floats per out chunk

__device__ __forceinline__ float bflo(unsigned u) { return __uint_as_float(u << 16); }
__device__ __forceinline__ float bfhi(unsigned u) { return __uint_as_float(u & 0xffff0000u); }
__device__ __forceinline__ float ldf(const void* p, size_t i, int isbf) {
  return isbf ? __uint_as_float(((unsigned)((const unsigned short*)p)[i]) << 16)
              : ((const float*)p)[i];
}

template<int CTRL>
__device__ __forceinline__ float dpp_add(float v) {
  int r = __builtin_amdgcn_mov_dpp(__float_as_int(v), CTRL, 0xF, 0xF, true);
  return v + __int_as_float(r);
}

__device__ __forceinline__ float sigm(float x) {
  return __builtin_amdgcn_rcpf(1.f + __expf(-x));
}
__device__ __forceinline__ float tanh_f(float x) {
  return fmaf(2.f, __builtin_amdgcn_rcpf(1.f + __expf(-2.f * x)), -1.f);
}

__global__ __launch_bounds__(256) void k_detect(const unsigned* __restrict__ bits,
                                                unsigned* __restrict__ flag) {
  __shared__ int cnt;
  if (threadIdx.x == 0) cnt = 0;
  __syncthreads();
  int local = 0;
  for (int i = threadIdx.x; i < 1024; i += 256) {
    unsigned e = (bits[i] >> 7) & 0xff;
    if (e >= 118 && e <= 134) local++;
  }
  atomicAdd(&cnt, local);
  __syncthreads();
  if (threadIdx.x == 0) *flag = (cnt > 768) ? 1u : 0u;
}

__global__ __launch_bounds__(256) void k_embed(const int* __restrict__ idx,
                                               const void* __restrict__ emb,
                                               const unsigned* __restrict__ flag,
                                               float* __restrict__ x0) {
  int isbf = (int)*flag;
  int i = blockIdx.x * 256 + threadIdx.x;
  int h = i & (HH - 1);
  int tb = i >> 7;
  x0[i] = ldf(emb, (size_t)idx[tb] * HH + h, isbf);
}

// C[M,512] = A[M,K] @ W[512,K]^T + bias ; grid (M/64, 8)   (L0 + fallback path)
__global__ __launch_bounds__(256) void k_proj(const float* __restrict__ A,
                                              const void* __restrict__ W, size_t w_off,
                                              const void* __restrict__ bias, size_t b_off,
                                              float* __restrict__ C, int K,
                                              const unsigned* __restrict__ flag) {
  int isbf = (int)*flag;
  __shared__ float As[16][68];
  __shared__ float Bs[16][68];
  int tid = threadIdx.x;
  int tx = tid & 15, ty = tid >> 4;
  int m_base = blockIdx.x * 64, n_base = blockIdx.y * 64;
  float acc[4][4] = {};
  int kk = tid & 15, rr = tid >> 4;
  for (int k0 = 0; k0 < K; k0 += 16) {
    #pragma unroll
    for (int r = 0; r < 4; r++) {
      As[kk][rr + 16*r] = A[(size_t)(m_base + rr + 16*r) * K + k0 + kk];
      Bs[kk][rr + 16*r] = ldf(W, w_off + (size_t)(n_base + rr + 16*r) * K + k0 + kk, isbf);
    }
    __syncthreads();
    #pragma unroll
    for (int k = 0; k < 16; k++) {
      float4 av = *(const float4*)(&As[k][ty*4]);
      float4 bv = *(const float4*)(&Bs[k][tx*4]);
      float a[4] = {av.x, av.y, av.z, av.w};
      float b[4] = {bv.x, bv.y, bv.z, bv.w};
      #pragma unroll
      for (int i = 0; i < 4; i++)
        #pragma unroll
        for (int j = 0; j < 4; j++)
          acc[i][j] += a[i] * b[j];
    }
    __syncthreads();
  }
  #pragma unroll
  for (int i = 0; i < 4; i++) {
    #pragma unroll
    for (int j = 0; j < 4; j++) {
      int n = n_base + tx*4 + j;
      C[(size_t)(m_base + ty*4 + i) * GG + n] = acc[i][j] + ldf(bias, b_off + n, isbf);
    }
  }
}

// L0 + fallback recurrent kernel (full-T). One block per (batch, direction).
__global__ __launch_bounds__(512, 2) void k_recur(
    const float* __restrict__ xg, size_t xg_dstride,
    const void* __restrict__ whh, size_t w_off, size_t w_dstride,
    float* __restrict__ hout, int hout_stride, int hout_doff,
    const float* __restrict__ res,
    float* __restrict__ hfin, float* __restrict__ cfin,
    int bidir, const unsigned* __restrict__ flag) {
  int isbf = (int)*flag;
  int d = blockIdx.x >> 6;
  int b = blockIdx.x & 63;
  int dir = (bidir == 2 || (bidir == 1 && d)) ? -1 : 1;
  xg += (size_t)d * xg_dstride;
  size_t woff = w_off + (size_t)d * w_dstride;
  int hcol = hout_doff * d;

  int t0 = threadIdx.x;
  int j = t0 >> 2, q = t0 & 3;

  // W_hh fragment, rotated by q chunks for bank-conflict-free broadcast reads
  float w[4][32];
  size_t wbase = woff + (size_t)j * HH + q * 32;
  if (isbf) {
    const uint4* wp = (const uint4*)whh;
    #pragma unroll
    for (int g = 0; g < 4; g++) {
      size_t b8 = (wbase + (size_t)g * 128 * HH) >> 3;
      #pragma unroll
      for (int u = 0; u < 4; u++) {
        uint4 v = wp[b8 + ((u + q) & 3)];
        w[g][u*8+0] = bflo(v.x); w[g][u*8+1] = bfhi(v.x);
        w[g][u*8+2] = bflo(v.y); w[g][u*8+3] = bfhi(v.y);
        w[g][u*8+4] = bflo(v.z); w[g][u*8+5] = bfhi(v.z);
        w[g][u*8+6] = bflo(v.w); w[g][u*8+7] = bfhi(v.w);
      }
    }
  } else {
    const float4* wp = (const float4*)whh;
    #pragma unroll
    for (int g = 0; g < 4; g++) {
      size_t b4 = (wbase + (size_t)g * 128 * HH) >> 2;
      #pragma unroll
      for (int u = 0; u < 8; u++) {
        float4 v = wp[b4 + ((u + 2*q) & 7)];
        w[g][u*4+0] = v.x; w[g][u*4+1] = v.y; w[g][u*4+2] = v.z; w[g][u*4+3] = v.w;
      }
    }
  }

  __shared__ float h_lds[2][HH];
  if (t0 < HH) h_lds[0][t0] = 0.f;
  float c = 0.f;

  int tfirst = (dir > 0) ? 0 : (TT - 1);
  size_t rg0 = ((size_t)tfirst * BB + b) * GG;
  float xg_cur[4];
  #pragma unroll
  for (int g = 0; g < 4; g++) xg_cur[g] = xg[rg0 + g * HH + j];
  float res_cur = res ? res[((size_t)tfirst * BB + b) * HH + j] : 0.f;
  __syncthreads();

  const float* hc = h_lds[0];
  float* hn = h_lds[1];

  #pragma unroll 1
  for (int s = 0; s < TT; s++) {
    int t = (dir > 0) ? s : (TT - 1 - s);
    float xg_nxt[4] = {0.f, 0.f, 0.f, 0.f};
    float res_nxt = 0.f;
    if (s + 1 < TT) {
      int tn = (dir > 0) ? (s + 1) : (TT - 2 - s);
      size_t rg = ((size_t)tn * BB + b) * GG;
      #pragma unroll
      for (int g = 0; g < 4; g++) xg_nxt[g] = xg[rg + g * HH + j];
      if (res) res_nxt = res[((size_t)tn * BB + b) * HH + j];
    }
    float p0 = 0.f, p1 = 0.f, p2 = 0.f, p3 = 0.f;
    const float4* hq = (const float4*)(hc + (q << 5));
    #pragma unroll
    for (int u = 0; u < 8; u++) {
      float4 hv = hq[(u + 2*q) & 7];
      p0 = fmaf(w[0][u*4+0], hv.x, p0); p0 = fmaf(w[0][u*4+1], hv.y, p0);
      p0 = fmaf(w[0][u*4+2], hv.z, p0); p0 = fmaf(w[0][u*4+3], hv.w, p0);
      p1 = fmaf(w[1][u*4+0], hv.x, p1); p1 = fmaf(w[1][u*4+1], hv.y, p1);
      p1 = fmaf(w[1][u*4+2], hv.z, p1); p1 = fmaf(w[1][u*4+3], hv.w, p1);
      p2 = fmaf(w[2][u*4+0], hv.x, p2); p2 = fmaf(w[2][u*4+1], hv.y, p2);
      p2 = fmaf(w[2][u*4+2], hv.z, p2); p2 = fmaf(w[2][u*4+3], hv.w, p2);
      p3 = fmaf(w[3][u*4+0], hv.x, p3); p3 = fmaf(w[3][u*4+1], hv.y, p3);
      p3 = fmaf(w[3][u*4+2], hv.z, p3); p3 = fmaf(w[3][u*4+3], hv.w, p3);
    }
    p0 = dpp_add<0xB1>(p0); p0 = dpp_add<0x4E>(p0);
    p1 = dpp_add<0xB1>(p1); p1 = dpp_add<0x4E>(p1);
    p2 = dpp_add<0xB1>(p2); p2 = dpp_add<0x4E>(p2);
    p3 = dpp_add<0xB1>(p3); p3 = dpp_add<0x4E>(p3);

    float gi = p0 + xg_cur[0], gf = p1 + xg_cur[1];
    float gc = p2 + xg_cur[2], go = p3 + xg_cur[3];
    float si = sigm(gi), sf = sigm(gf), so = sigm(go);
    c = fmaf(sf, c, si * tanh_f(gc));
    float h = so * tanh_f(c);

    if (q == 0) {
      hn[j] = h;
      hout[((size_t)t * BB + b) * hout_stride + hcol + j] = h + res_cur;
      if (t == TT - 1) hfin[(size_t)(d * BB + b) * HH + j] = h;
    }
    #pragma unroll
    for (int g = 0; g < 4; g++) xg_cur[g] = xg_nxt[g];
    res_cur = res_nxt;
    __syncthreads();
    const float* tmp = hc; hc = hn; hn = (float*)tmp;
  }
  if (q == 0) cfin[(size_t)(d * BB + b) * HH + j] = c;
}

// ---------------- wavefront kernel: layers 1..7, chunked ----------------
// Block = (layer-slot, batch). Phase 1 (prologue): GEMM next chunk's xg.
// Phase 2: 64-step recurrence on current chunk (identical math to k_recur).
struct WaveDesc { int n; int r[5]; int k[5]; };

__global__ __launch_bounds__(512, 2) void k_wave(
    WaveDesc wd,
    float* __restrict__ xg_f, float* __restrict__ xg_b,
    const float* __restrict__ xcat, float* __restrict__ out7,
    const void* __restrict__ w_ih1, const void* __restrict__ w_hh1, const void* __restrict__ b1,
    const void* __restrict__ w_ihr, const void* __restrict__ w_hhr, const void* __restrict__ br,
    const unsigned* __restrict__ flag) {
  int isbf = (int)*flag;
  int slot = blockIdx.x >> 6;
  int b = blockIdx.x & 63;
  int r = wd.r[slot];
  int k = wd.k[slot];

  float* outring = xg_b + 2 * (size_t)CHGG;          // 18 slots of CHH (6 layers x ring 3)
  float* hstate  = outring + 18 * (size_t)CHH;       // [7][BB][HH]
  float* cstate  = hstate + 7 * (size_t)BH;

  // xg slot for layer rr, parity p
  auto xgslot = [&](int rr, int p) -> float* {
    int sl = (rr % 5) * 2 + p;
    return (sl < 8) ? (xg_f + (size_t)sl * CHGG) : (xg_b + (size_t)(sl - 8) * CHGG);
  };
  // output chunk base for layer rr (1..7), chunk kk; layout [t_loc][b][HH]
  auto outchunk = [&](int rr, int kk) -> float* {
    if (rr == 7) return out7 + (size_t)kk * CH * BB * HH;
    return outring + ((size_t)(rr - 1) * 3 + (kk % 3)) * CHH;
  };

  __shared__ float Ap[16][68];
  __shared__ float Bs0[16][68];
  __shared__ float Bs1[16][68];
  __shared__ float h_lds[2][HH];

  // ---------------- prologue: xg(r, k+1) for this batch ----------------
  int kp = k + 1;
  if (kp < NCH) {
    int K = (r == 1) ? 2 * HH : HH;
    const float* Abase;
    if (r == 1) Abase = xcat + ((size_t)(kp * CH) * BB + b) * (2 * HH);
    else        Abase = outchunk(r - 1, kp) + (size_t)b * HH;
    const void* Wv; size_t wo; const void* Bv; size_t bo;
    if (r == 1) { Wv = w_ih1; wo = 0; Bv = b1; bo = 0; }
    else { Wv = w_ihr; wo = (size_t)(r - 2) * GG * HH; Bv = br; bo = (size_t)(r - 2) * GG; }
    float* Cbase = xgslot(r, kp & 1) + (size_t)b * GG;  // row t at + t*BB*GG

    int tid = threadIdx.x;
    int h2 = tid >> 8;
    int t8 = tid & 255;
    int tx = t8 & 15, ty = t8 >> 4;
    int kk = t8 & 15, rr = t8 >> 4;
    size_t Astride = (size_t)BB * K;  // row stride of A in memory
    for (int ct = 0; ct < 4; ct++) {
      int n_base = (ct * 2 + h2) * 64;
      float acc[4][4] = {};
      for (int k0 = 0; k0 < K; k0 += 16) {
        if (h2 == 0) {
          #pragma unroll
          for (int rx = 0; rx < 4; rx++)
            Ap[kk][rr + 16*rx] = Abase[(size_t)(rr + 16*rx) * Astride + k0 + kk];
        }
        {
          float (*Bsx)[68] = h2 ? Bs1 : Bs0;
          #pragma unroll
          for (int rx = 0; rx < 4; rx++)
            Bsx[kk][rr + 16*rx] = ldf(Wv, wo + (size_t)(n_base + rr + 16*rx) * K + k0 + kk, isbf);
        }
        __syncthreads();
        float (*Bsx)[68] = h2 ? Bs1 : Bs0;
        #pragma unroll
        for (int kq = 0; kq < 16; kq++) {
          float4 av = *(const float4*)(&Ap[kq][ty*4]);
          float4 bv = *(const float4*)(&Bsx[kq][tx*4]);
          float a[4] = {av.x, av.y, av.z, av.w};
          float bb2[4] = {bv.x, bv.y, bv.z, bv.w};
          #pragma unroll
          for (int i = 0; i < 4; i++)
            #pragma unroll
            for (int jx = 0; jx < 4; jx++)
              acc[i][jx] += a[i] * bb2[jx];
        }
        __syncthreads();
      }
      #pragma unroll
      for (int i = 0; i < 4; i++) {
        #pragma unroll
        for (int jx = 0; jx < 4; jx++) {
          int n = n_base + tx*4 + jx;
          Cbase[(size_t)(ty*4 + i) * BB * GG + n] = acc[i][jx] + ldf(Bv, bo + n, isbf);
        }
      }
    }
  }

  // ---------------- recur: chunk k of layer r ----------------
  if (k < 0) return;  // proj-only bootstrap block

  const void* whh = (r == 1) ? w_hh1 : w_hhr;
  size_t woff = (r == 1) ? 0 : (size_t)(r - 2) * GG * HH;
  const float* xg = xgslot(r, k & 1);
  const float* resb = (r >= 2) ? (outchunk(r - 1, k) + (size_t)b * HH) : nullptr;
  float* houtb = outchunk(r, k) + (size_t)b * HH;
  float* hst = hstate + (size_t)(r - 1) * BH + (size_t)b * HH;
  float* cst = cstate + (size_t)(r - 1) * BH + (size_t)b * HH;

  int t0 = threadIdx.x;
  int j = t0 >> 2, q = t0 & 3;

  float w[4][32];
  size_t wbase = woff + (size_t)j * HH + q * 32;
  if (isbf) {
    const uint4* wp = (const uint4*)whh;
    #pragma unroll
    for (int g = 0; g < 4; g++) {
      size_t b8 = (wbase + (size_t)g * 128 * HH) >> 3;
      #pragma unroll
      for (int u = 0; u < 4; u++) {
        uint4 v = wp[b8 + ((u + q) & 3)];
        w[g][u*8+0] = bflo(v.x); w[g][u*8+1] = bfhi(v.x);
        w[g][u*8+2] = bflo(v.y); w[g][u*8+3] = bfhi(v.y);
        w[g][u*8+4] = bflo(v.z); w[g][u*8+5] = bfhi(v.z);
        w[g][u*8+6] = bflo(v.w); w[g][u*8+7] = bfhi(v.w);
      }
    }
  } else {
    const float4* wp = (const float4*)whh;
    #pragma unroll
    for (int g = 0; g < 4; g++) {
      size_t b4 = (wbase + (size_t)g * 128 * HH) >> 2;
      #pragma unroll
      for (int u = 0; u < 8; u++) {
        float4 v = wp[b4 + ((u + 2*q) & 7)];
        w[g][u*4+0] = v.x; w[g][u*4+1] = v.y; w[g][u*4+2] = v.z; w[g][u*4+3] = v.w;
      }
    }
  }

  if (t0 < HH) h_lds[0][t0] = k ? hst[t0] : 0.f;
  float c = k ? cst[j] : 0.f;

  size_t rg0 = (size_t)b * GG;  // t_loc = 0
  float xg_cur[4];
  #pragma unroll
  for (int g = 0; g < 4; g++) xg_cur[g] = xg[rg0 + g * HH + j];
  float res_cur = resb ? resb[j] : 0.f;
  __syncthreads();

  const float* hc = h_lds[0];
  float* hn = h_lds[1];

  #pragma unroll 1
  for (int s = 0; s < CH; s++) {
    float xg_nxt[4] = {0.f, 0.f, 0.f, 0.f};
    float res_nxt = 0.f;
    if (s + 1 < CH) {
      size_t rg = ((size_t)(s + 1) * BB + b) * GG;
      #pragma unroll
      for (int g = 0; g < 4; g++) xg_nxt[g] = xg[rg + g * HH + j];
      if (resb) res_nxt = resb[(size_t)(s + 1) * BB * HH + j];
    }
    float p0 = 0.f, p1 = 0.f, p2 = 0.f, p3 = 0.f;
    const float4* hq = (const float4*)(hc + (q << 5));
    #pragma unroll
    for (int u = 0; u < 8; u++) {
      float4 hv = hq[(u + 2*q) & 7];
      p0 = fmaf(w[0][u*4+0], hv.x, p0); p0 = fmaf(w[0][u*4+1], hv.y, p0);
      p0 = fmaf(w[0][u*4+2], hv.z, p0); p0 = fmaf(w[0][u*4+3], hv.w, p0);
      p1 = fmaf(w[1][u*4+0], hv.x, p1); p1 = fmaf(w[1][u*4+1], hv.y, p1);
      p1 = fmaf(w[1][u*4+2], hv.z, p1); p1 = fmaf(w[1][u*4+3], hv.w, p1);
      p2 = fmaf(w[2][u*4+0], hv.x, p2); p2 = fmaf(w[2][u*4+1], hv.y, p2);
      p2 = fmaf(w[2][u*4+2], hv.z, p2); p2 = fmaf(w[2][u*4+3], hv.w, p2);
      p3 = fmaf(w[3][u*4+0], hv.x, p3); p3 = fmaf(w[3][u*4+1], hv.y, p3);
      p3 = fmaf(w[3][u*4+2], hv.z, p3); p3 = fmaf(w[3][u*4+3], hv.w, p3);
    }
    p0 = dpp_add<0xB1>(p0); p0 = dpp_add<0x4E>(p0);
    p1 = dpp_add<0xB1>(p1); p1 = dpp_add<0x4E>(p1);
    p2 = dpp_add<0xB1>(p2); p2 = dpp_add<0x4E>(p2);
    p3 = dpp_add<0xB1>(p3); p3 = dpp_add<0x4E>(p3);

    float gi = p0 + xg_cur[0], gf = p1 + xg_cur[1];
    float gc = p2 + xg_cur[2], go = p3 + xg_cur[3];
    float si = sigm(gi), sf = sigm(gf), so = sigm(go);
    c = fmaf(sf, c, si * tanh_f(gc));
    float h = so * tanh_f(c);

    if (q == 0) {
      hn[j] = h;
      houtb[(size_t)s * BB * HH + j] = h + res_cur;
      if (s == CH - 1) hst[j] = h;   // raw h for next chunk's state
    }
    #pragma unroll
    for (int g = 0; g < 4; g++) xg_cur[g] = xg_nxt[g];
    res_cur = res_nxt;
    __syncthreads();
    const float* tmp = hc; hc = hn; hn = (float*)tmp;
  }
  if (q == 0) cst[j] = c;
}

__global__ __launch_bounds__(256) void k_out(const float* __restrict__ x,
                                             const float* __restrict__ hfin,
                                             const float* __restrict__ cfin,
                                             void* __restrict__ out,
                                             const unsigned* __restrict__ flag) {
  int isbf = (int)*flag;
  int i = blockIdx.x * 256 + threadIdx.x;
  float v;
  if (i < TBH) v = x[i];
  else if (i < TBH + BH) v = hfin[i - TBH];
  else v = cfin[i - TBH - BH];
  if (isbf) ((__hip_bfloat16*)out)[i] = __float2bfloat16(v);
  else ((float*)out)[i] = v;
}

extern "C" void kernel_launch(void* const* d_in, const int* in_sizes, int n_in,
                              void* d_out, int out_size, void* d_ws, size_t ws_size,
                              hipStream_t stream) {
  const int* idx = (const int*)d_in[0];
  const void* emb   = d_in[1];
  const void* w_ih0 = d_in[2];
  const void* w_hh0 = d_in[3];
  const void* b0    = d_in[4];
  const void* w_ih1 = d_in[5];
  const void* w_hh1 = d_in[6];
  const void* b1    = d_in[7];
  const void* w_ihr = d_in[8];
  const void* w_hhr = d_in[9];
  const void* br    = d_in[10];

  float* ws   = (float*)d_ws;
  float* x0   = ws;                       // TBH   (L0 input; later: out7 full buffer)
  float* xcat = ws + TBH;                 // 2*TBH (L0 output / L1 input)
  float* xg_f = ws + 3 * (size_t)TBH;     // TBG   (L0 fwd xg; later: xg slots 0..7)
  float* hfin = ws + 3 * (size_t)TBH + TBG;        // 2*BH
  float* cfin = hfin + 2 * BH;                     // 2*BH
  unsigned* flag = (unsigned*)(cfin + 2 * BH);
  float* xg_b = cfin + 2 * BH + 16384;    // TBG (L0 bwd xg; later: slots 8..9 + rings + states)
  int merged = ws_size >= (size_t)(3 * (size_t)TBH + 2 * (size_t)TBG + 4 * BH + 16384 + 64) * 4;

  k_detect<<<1, 256, 0, stream>>>((const unsigned*)emb, flag);
  k_embed<<<TBH / 256, 256, 0, stream>>>(idx, emb, flag, x0);

  dim3 pg(512, 8);
  if (merged) {
    // ---- layer 0 (bidirectional), as before ----
    k_proj<<<pg, 256, 0, stream>>>(x0, w_ih0, 0, b0, 0, xg_f, HH, flag);
    k_proj<<<pg, 256, 0, stream>>>(x0, w_ih0, (size_t)GG * HH, b0, GG, xg_b, HH, flag);
    k_recur<<<128, 512, 0, stream>>>(xg_f, (size_t)(xg_b - xg_f), w_hh0, 0, (size_t)GG * HH,
                                     xcat, 2 * HH, HH, nullptr, hfin, cfin, 1, flag);

    // ---- layers 1..7: chunked wavefront ----
    // recur(r,k) at wave w = 2(r-1)+k+1 ; proj-only (r,-1) at w = 2(r-1).
    float* outring = xg_b + 2 * (size_t)CHGG;
    float* hstate  = outring + 18 * (size_t)CHH;
    float* cstate  = hstate + 7 * (size_t)BH;
    for (int wv = 0; wv <= 2 * 6 + (NCH - 1) + 1; wv++) {
      WaveDesc wd; wd.n = 0;
      for (int r = 1; r <= 7; r++) {
        int kk = wv - 2 * (r - 1) - 1;
        if (kk >= 0 && kk < NCH) { wd.r[wd.n] = r; wd.k[wd.n] = kk; wd.n++; }
      }
      for (int r = 1; r <= 7; r++) {
        int kk = wv - 2 * (r - 1) - 1;
        if (kk == -1) { wd.r[wd.n] = r; wd.k[wd.n] = kk; wd.n++; }
      }
      if (wd.n)
        k_wave<<<wd.n * 64, 512, 0, stream>>>(wd, xg_f, xg_b, xcat, x0,
                                              w_ih1, w_hh1, b1, w_ihr, w_hhr, br, flag);
    }
    k_out<<<(TBH + 2 * BH) / 256, 256, 0, stream>>>(x0, hstate + 6 * BH, cstate + 6 * BH,
                                                    d_out, flag);
  } else {
    // ---- fallback: original fully-serial path ----
    k_proj<<<pg, 256, 0, stream>>>(x0, w_ih0, 0, b0, 0, xg_f, HH, flag);
    k_recur<<<64, 512, 0, stream>>>(xg_f, 0, w_hh0, 0, 0,
                                    xcat, 2 * HH, 0, nullptr, hfin, cfin, 0, flag);
    k_proj<<<pg, 256, 0, stream>>>(x0, w_ih0, (size_t)GG * HH, b0, GG, xg_f, HH, flag);
    k_recur<<<64, 512, 0, stream>>>(xg_f, 0, w_hh0, (size_t)GG * HH, 0,
                                    xcat + HH, 2 * HH, 0, nullptr, hfin, cfin, 2, flag);
    float* xA = xcat;
    float* xB = xcat + TBH;
    k_proj<<<pg, 256, 0, stream>>>(xcat, w_ih1, 0, b1, 0, xg_f, 2 * HH, flag);
    k_recur<<<64, 512, 0, stream>>>(xg_f, 0, w_hh1, 0, 0, xA, HH, 0, nullptr, hfin, cfin, 0, flag);
    float* cur = xA;
    float* nxt = xB;
    for (int r = 0; r < 6; r++) {
      k_proj<<<pg, 256, 0, stream>>>(cur, w_ihr, (size_t)r * GG * HH, br, (size_t)r * GG, xg_f, HH, flag);
      k_recur<<<64, 512, 0, stream>>>(xg_f, 0, w_hhr, (size_t)r * GG * HH, 0,
                                      nxt, HH, 0, cur, hfin, cfin, 0, flag);
      float* t = cur; cur = nxt; nxt = t;
    }
    k_out<<<(TBH + 2 * BH) / 256, 256, 0, stream>>>(cur, hfin, cfin, d_out, flag);
  }
}

// Round 3
// 3059.965 us; speedup vs baseline: 1.2976x; 1.1297x over previous
//
#include <hip/hip_runtime.h>
#include <hip/hip_bf16.h>

#define TT 512
#define BB 64
#define HH 128
#define GG 512   // 4*H
#define TBH (TT*BB*HH)
#define TBG (TT*BB*GG)
#define BH (BB*HH)
#define CH 64                 // wavefront chunk length (timesteps)
#define NCH (TT/CH)           // 8 chunks
#define CHGG (CH*BB*GG)       // floats per xg chunk slot
#define CHH (CH*BB*HH)        // floats per out chunk

__device__ __forceinline__ float bflo(unsigned u) { return __uint_as_float(u << 16); }
__device__ __forceinline__ float bfhi(unsigned u) { return __uint_as_float(u & 0xffff0000u); }
__device__ __forceinline__ float ldf(const void* p, size_t i, int isbf) {
  return isbf ? __uint_as_float(((unsigned)((const unsigned short*)p)[i]) << 16)
              : ((const float*)p)[i];
}

template<int CTRL>
__device__ __forceinline__ float dpp_add(float v) {
  int r = __builtin_amdgcn_mov_dpp(__float_as_int(v), CTRL, 0xF, 0xF, true);
  return v + __int_as_float(r);
}

__device__ __forceinline__ float sigm(float x) {
  return __builtin_amdgcn_rcpf(1.f + __expf(-x));
}
__device__ __forceinline__ float tanh_f(float x) {
  return fmaf(2.f, __builtin_amdgcn_rcpf(1.f + __expf(-2.f * x)), -1.f);
}

__global__ __launch_bounds__(256) void k_detect(const unsigned* __restrict__ bits,
                                                unsigned* __restrict__ flag) {
  __shared__ int cnt;
  if (threadIdx.x == 0) cnt = 0;
  __syncthreads();
  int local = 0;
  for (int i = threadIdx.x; i < 1024; i += 256) {
    unsigned e = (bits[i] >> 7) & 0xff;
    if (e >= 118 && e <= 134) local++;
  }
  atomicAdd(&cnt, local);
  __syncthreads();
  if (threadIdx.x == 0) *flag = (cnt > 768) ? 1u : 0u;
}

__global__ __launch_bounds__(256) void k_embed(const int* __restrict__ idx,
                                               const void* __restrict__ emb,
                                               const unsigned* __restrict__ flag,
                                               float* __restrict__ x0) {
  int isbf = (int)*flag;
  int i = blockIdx.x * 256 + threadIdx.x;
  int h = i & (HH - 1);
  int tb = i >> 7;
  x0[i] = ldf(emb, (size_t)idx[tb] * HH + h, isbf);
}

// C[M,512] = A[M,K] @ W[512,K]^T + bias ; grid (M/64, 8)   (L0 + fallback path)
__global__ __launch_bounds__(256) void k_proj(const float* __restrict__ A,
                                              const void* __restrict__ W, size_t w_off,
                                              const void* __restrict__ bias, size_t b_off,
                                              float* __restrict__ C, int K,
                                              const unsigned* __restrict__ flag) {
  int isbf = (int)*flag;
  __shared__ float As[16][68];
  __shared__ float Bs[16][68];
  int tid = threadIdx.x;
  int tx = tid & 15, ty = tid >> 4;
  int m_base = blockIdx.x * 64, n_base = blockIdx.y * 64;
  float acc[4][4] = {};
  int kk = tid & 15, rr = tid >> 4;
  for (int k0 = 0; k0 < K; k0 += 16) {
    #pragma unroll
    for (int r = 0; r < 4; r++) {
      As[kk][rr + 16*r] = A[(size_t)(m_base + rr + 16*r) * K + k0 + kk];
      Bs[kk][rr + 16*r] = ldf(W, w_off + (size_t)(n_base + rr + 16*r) * K + k0 + kk, isbf);
    }
    __syncthreads();
    #pragma unroll
    for (int k = 0; k < 16; k++) {
      float4 av = *(const float4*)(&As[k][ty*4]);
      float4 bv = *(const float4*)(&Bs[k][tx*4]);
      float a[4] = {av.x, av.y, av.z, av.w};
      float b[4] = {bv.x, bv.y, bv.z, bv.w};
      #pragma unroll
      for (int i = 0; i < 4; i++)
        #pragma unroll
        for (int j = 0; j < 4; j++)
          acc[i][j] += a[i] * b[j];
    }
    __syncthreads();
  }
  #pragma unroll
  for (int i = 0; i < 4; i++) {
    #pragma unroll
    for (int j = 0; j < 4; j++) {
      int n = n_base + tx*4 + j;
      C[(size_t)(m_base + ty*4 + i) * GG + n] = acc[i][j] + ldf(bias, b_off + n, isbf);
    }
  }
}

// L0 + fallback recurrent kernel (full-T). One block per (batch, direction).
__global__ __launch_bounds__(512, 2) void k_recur(
    const float* __restrict__ xg, size_t xg_dstride,
    const void* __restrict__ whh, size_t w_off, size_t w_dstride,
    float* __restrict__ hout, int hout_stride, int hout_doff,
    const float* __restrict__ res,
    float* __restrict__ hfin, float* __restrict__ cfin,
    int bidir, const unsigned* __restrict__ flag) {
  int isbf = (int)*flag;
  int d = blockIdx.x >> 6;
  int b = blockIdx.x & 63;
  int dir = (bidir == 2 || (bidir == 1 && d)) ? -1 : 1;
  xg += (size_t)d * xg_dstride;
  size_t woff = w_off + (size_t)d * w_dstride;
  int hcol = hout_doff * d;

  int t0 = threadIdx.x;
  int j = t0 >> 2, q = t0 & 3;

  // W_hh fragment, rotated by q chunks for bank-conflict-free broadcast reads
  float w[4][32];
  size_t wbase = woff + (size_t)j * HH + q * 32;
  if (isbf) {
    const uint4* wp = (const uint4*)whh;
    #pragma unroll
    for (int g = 0; g < 4; g++) {
      size_t b8 = (wbase + (size_t)g * 128 * HH) >> 3;
      #pragma unroll
      for (int u = 0; u < 4; u++) {
        uint4 v = wp[b8 + ((u + q) & 3)];
        w[g][u*8+0] = bflo(v.x); w[g][u*8+1] = bfhi(v.x);
        w[g][u*8+2] = bflo(v.y); w[g][u*8+3] = bfhi(v.y);
        w[g][u*8+4] = bflo(v.z); w[g][u*8+5] = bfhi(v.z);
        w[g][u*8+6] = bflo(v.w); w[g][u*8+7] = bfhi(v.w);
      }
    }
  } else {
    const float4* wp = (const float4*)whh;
    #pragma unroll
    for (int g = 0; g < 4; g++) {
      size_t b4 = (wbase + (size_t)g * 128 * HH) >> 2;
      #pragma unroll
      for (int u = 0; u < 8; u++) {
        float4 v = wp[b4 + ((u + 2*q) & 7)];
        w[g][u*4+0] = v.x; w[g][u*4+1] = v.y; w[g][u*4+2] = v.z; w[g][u*4+3] = v.w;
      }
    }
  }

  __shared__ float h_lds[2][HH];
  if (t0 < HH) h_lds[0][t0] = 0.f;
  float c = 0.f;

  int tfirst = (dir > 0) ? 0 : (TT - 1);
  size_t rg0 = ((size_t)tfirst * BB + b) * GG;
  float xg_cur[4];
  #pragma unroll
  for (int g = 0; g < 4; g++) xg_cur[g] = xg[rg0 + g * HH + j];
  float res_cur = res ? res[((size_t)tfirst * BB + b) * HH + j] : 0.f;
  __syncthreads();

  const float* hc = h_lds[0];
  float* hn = h_lds[1];

  #pragma unroll 1
  for (int s = 0; s < TT; s++) {
    int t = (dir > 0) ? s : (TT - 1 - s);
    float xg_nxt[4] = {0.f, 0.f, 0.f, 0.f};
    float res_nxt = 0.f;
    if (s + 1 < TT) {
      int tn = (dir > 0) ? (s + 1) : (TT - 2 - s);
      size_t rg = ((size_t)tn * BB + b) * GG;
      #pragma unroll
      for (int g = 0; g < 4; g++) xg_nxt[g] = xg[rg + g * HH + j];
      if (res) res_nxt = res[((size_t)tn * BB + b) * HH + j];
    }
    float p0 = 0.f, p1 = 0.f, p2 = 0.f, p3 = 0.f;
    const float4* hq = (const float4*)(hc + (q << 5));
    #pragma unroll
    for (int u = 0; u < 8; u++) {
      float4 hv = hq[(u + 2*q) & 7];
      p0 = fmaf(w[0][u*4+0], hv.x, p0); p0 = fmaf(w[0][u*4+1], hv.y, p0);
      p0 = fmaf(w[0][u*4+2], hv.z, p0); p0 = fmaf(w[0][u*4+3], hv.w, p0);
      p1 = fmaf(w[1][u*4+0], hv.x, p1); p1 = fmaf(w[1][u*4+1], hv.y, p1);
      p1 = fmaf(w[1][u*4+2], hv.z, p1); p1 = fmaf(w[1][u*4+3], hv.w, p1);
      p2 = fmaf(w[2][u*4+0], hv.x, p2); p2 = fmaf(w[2][u*4+1], hv.y, p2);
      p2 = fmaf(w[2][u*4+2], hv.z, p2); p2 = fmaf(w[2][u*4+3], hv.w, p2);
      p3 = fmaf(w[3][u*4+0], hv.x, p3); p3 = fmaf(w[3][u*4+1], hv.y, p3);
      p3 = fmaf(w[3][u*4+2], hv.z, p3); p3 = fmaf(w[3][u*4+3], hv.w, p3);
    }
    p0 = dpp_add<0xB1>(p0); p0 = dpp_add<0x4E>(p0);
    p1 = dpp_add<0xB1>(p1); p1 = dpp_add<0x4E>(p1);
    p2 = dpp_add<0xB1>(p2); p2 = dpp_add<0x4E>(p2);
    p3 = dpp_add<0xB1>(p3); p3 = dpp_add<0x4E>(p3);

    float gi = p0 + xg_cur[0], gf = p1 + xg_cur[1];
    float gc = p2 + xg_cur[2], go = p3 + xg_cur[3];
    float si = sigm(gi), sf = sigm(gf), so = sigm(go);
    c = fmaf(sf, c, si * tanh_f(gc));
    float h = so * tanh_f(c);

    if (q == 0) {
      hn[j] = h;
      hout[((size_t)t * BB + b) * hout_stride + hcol + j] = h + res_cur;
      if (t == TT - 1) hfin[(size_t)(d * BB + b) * HH + j] = h;
    }
    #pragma unroll
    for (int g = 0; g < 4; g++) xg_cur[g] = xg_nxt[g];
    res_cur = res_nxt;
    __syncthreads();
    const float* tmp = hc; hc = hn; hn = (float*)tmp;
  }
  if (q == 0) cfin[(size_t)(d * BB + b) * HH + j] = c;
}

// ---------------- wavefront kernel: layers 1..7, chunked ----------------
// Each BLOCK is either a recur cell (role 0) or a proj cell (role 1).
// proj(r,k) scheduled at wave 2r-2+k; recur(r,k) at wave 2r-1+k. Cells in the
// same wave are mutually independent (both read only wave<wv outputs), so
// recur blocks (latency-bound) and proj blocks (issue-bound) overlap on CUs.
struct WaveDesc { int n; int r[8]; int k[8]; int role[8]; };

__global__ __launch_bounds__(512, 2) void k_wave(
    WaveDesc wd,
    float* __restrict__ xg_f, float* __restrict__ xg_b,
    const float* __restrict__ xcat, float* __restrict__ out7,
    const void* __restrict__ w_ih1, const void* __restrict__ w_hh1, const void* __restrict__ b1,
    const void* __restrict__ w_ihr, const void* __restrict__ w_hhr, const void* __restrict__ br,
    const unsigned* __restrict__ flag) {
  int isbf = (int)*flag;
  int slot = blockIdx.x >> 6;
  int b = blockIdx.x & 63;
  int r = wd.r[slot];
  int k = wd.k[slot];
  int role = wd.role[slot];

  float* outring = xg_b + 2 * (size_t)CHGG;          // 18 slots of CHH (6 layers x ring 3)
  float* hstate  = outring + 18 * (size_t)CHH;       // [7][BB][HH]
  float* cstate  = hstate + 7 * (size_t)BH;

  // xg slot for layer rr, parity p
  auto xgslot = [&](int rr, int p) -> float* {
    int sl = (rr % 5) * 2 + p;
    return (sl < 8) ? (xg_f + (size_t)sl * CHGG) : (xg_b + (size_t)(sl - 8) * CHGG);
  };
  // output chunk base for layer rr (1..7), chunk kk; layout [t_loc][b][HH]
  auto outchunk = [&](int rr, int kk) -> float* {
    if (rr == 7) return out7 + (size_t)kk * CH * BB * HH;
    return outring + ((size_t)(rr - 1) * 3 + (kk % 3)) * CHH;
  };

  __shared__ float Ap[16][68];
  __shared__ float Bs0[16][68];
  __shared__ float Bs1[16][68];
  __shared__ float h_lds[2][HH];

  if (role == 1) {
    // ---------------- proj cell: xg(r, k) for this batch ----------------
    int K = (r == 1) ? 2 * HH : HH;
    const float* Abase;
    if (r == 1) Abase = xcat + ((size_t)(k * CH) * BB + b) * (2 * HH);
    else        Abase = outchunk(r - 1, k) + (size_t)b * HH;
    const void* Wv; size_t wo; const void* Bv; size_t bo;
    if (r == 1) { Wv = w_ih1; wo = 0; Bv = b1; bo = 0; }
    else { Wv = w_ihr; wo = (size_t)(r - 2) * GG * HH; Bv = br; bo = (size_t)(r - 2) * GG; }
    float* Cbase = xgslot(r, k & 1) + (size_t)b * GG;  // row t at + t*BB*GG

    int tid = threadIdx.x;
    int h2 = tid >> 8;
    int t8 = tid & 255;
    int tx = t8 & 15, ty = t8 >> 4;
    int kk = t8 & 15, rr = t8 >> 4;
    size_t Astride = (size_t)BB * K;  // row stride of A in memory
    for (int ct = 0; ct < 4; ct++) {
      int n_base = (ct * 2 + h2) * 64;
      float acc[4][4] = {};
      for (int k0 = 0; k0 < K; k0 += 16) {
        if (h2 == 0) {
          #pragma unroll
          for (int rx = 0; rx < 4; rx++)
            Ap[kk][rr + 16*rx] = Abase[(size_t)(rr + 16*rx) * Astride + k0 + kk];
        }
        {
          float (*Bsx)[68] = h2 ? Bs1 : Bs0;
          #pragma unroll
          for (int rx = 0; rx < 4; rx++)
            Bsx[kk][rr + 16*rx] = ldf(Wv, wo + (size_t)(n_base + rr + 16*rx) * K + k0 + kk, isbf);
        }
        __syncthreads();
        float (*Bsx)[68] = h2 ? Bs1 : Bs0;
        #pragma unroll
        for (int kq = 0; kq < 16; kq++) {
          float4 av = *(const float4*)(&Ap[kq][ty*4]);
          float4 bv = *(const float4*)(&Bsx[kq][tx*4]);
          float a[4] = {av.x, av.y, av.z, av.w};
          float bb2[4] = {bv.x, bv.y, bv.z, bv.w};
          #pragma unroll
          for (int i = 0; i < 4; i++)
            #pragma unroll
            for (int jx = 0; jx < 4; jx++)
              acc[i][jx] += a[i] * bb2[jx];
        }
        __syncthreads();
      }
      #pragma unroll
      for (int i = 0; i < 4; i++) {
        #pragma unroll
        for (int jx = 0; jx < 4; jx++) {
          int n = n_base + tx*4 + jx;
          Cbase[(size_t)(ty*4 + i) * BB * GG + n] = acc[i][jx] + ldf(Bv, bo + n, isbf);
        }
      }
    }
    return;
  }

  // ---------------- recur cell: chunk k of layer r ----------------
  const void* whh = (r == 1) ? w_hh1 : w_hhr;
  size_t woff = (r == 1) ? 0 : (size_t)(r - 2) * GG * HH;
  const float* xg = xgslot(r, k & 1);
  const float* resb = (r >= 2) ? (outchunk(r - 1, k) + (size_t)b * HH) : nullptr;
  float* houtb = outchunk(r, k) + (size_t)b * HH;
  float* hst = hstate + (size_t)(r - 1) * BH + (size_t)b * HH;
  float* cst = cstate + (size_t)(r - 1) * BH + (size_t)b * HH;

  int t0 = threadIdx.x;
  int j = t0 >> 2, q = t0 & 3;

  float w[4][32];
  size_t wbase = woff + (size_t)j * HH + q * 32;
  if (isbf) {
    const uint4* wp = (const uint4*)whh;
    #pragma unroll
    for (int g = 0; g < 4; g++) {
      size_t b8 = (wbase + (size_t)g * 128 * HH) >> 3;
      #pragma unroll
      for (int u = 0; u < 4; u++) {
        uint4 v = wp[b8 + ((u + q) & 3)];
        w[g][u*8+0] = bflo(v.x); w[g][u*8+1] = bfhi(v.x);
        w[g][u*8+2] = bflo(v.y); w[g][u*8+3] = bfhi(v.y);
        w[g][u*8+4] = bflo(v.z); w[g][u*8+5] = bfhi(v.z);
        w[g][u*8+6] = bflo(v.w); w[g][u*8+7] = bfhi(v.w);
      }
    }
  } else {
    const float4* wp = (const float4*)whh;
    #pragma unroll
    for (int g = 0; g < 4; g++) {
      size_t b4 = (wbase + (size_t)g * 128 * HH) >> 2;
      #pragma unroll
      for (int u = 0; u < 8; u++) {
        float4 v = wp[b4 + ((u + 2*q) & 7)];
        w[g][u*4+0] = v.x; w[g][u*4+1] = v.y; w[g][u*4+2] = v.z; w[g][u*4+3] = v.w;
      }
    }
  }

  if (t0 < HH) h_lds[0][t0] = k ? hst[t0] : 0.f;
  float c = k ? cst[j] : 0.f;

  size_t rg0 = (size_t)b * GG;  // t_loc = 0
  float xg_cur[4];
  #pragma unroll
  for (int g = 0; g < 4; g++) xg_cur[g] = xg[rg0 + g * HH + j];
  float res_cur = resb ? resb[j] : 0.f;
  __syncthreads();

  const float* hc = h_lds[0];
  float* hn = h_lds[1];

  #pragma unroll 1
  for (int s = 0; s < CH; s++) {
    float xg_nxt[4] = {0.f, 0.f, 0.f, 0.f};
    float res_nxt = 0.f;
    if (s + 1 < CH) {
      size_t rg = ((size_t)(s + 1) * BB + b) * GG;
      #pragma unroll
      for (int g = 0; g < 4; g++) xg_nxt[g] = xg[rg + g * HH + j];
      if (resb) res_nxt = resb[(size_t)(s + 1) * BB * HH + j];
    }
    float p0 = 0.f, p1 = 0.f, p2 = 0.f, p3 = 0.f;
    const float4* hq = (const float4*)(hc + (q << 5));
    #pragma unroll
    for (int u = 0; u < 8; u++) {
      float4 hv = hq[(u + 2*q) & 7];
      p0 = fmaf(w[0][u*4+0], hv.x, p0); p0 = fmaf(w[0][u*4+1], hv.y, p0);
      p0 = fmaf(w[0][u*4+2], hv.z, p0); p0 = fmaf(w[0][u*4+3], hv.w, p0);
      p1 = fmaf(w[1][u*4+0], hv.x, p1); p1 = fmaf(w[1][u*4+1], hv.y, p1);
      p1 = fmaf(w[1][u*4+2], hv.z, p1); p1 = fmaf(w[1][u*4+3], hv.w, p1);
      p2 = fmaf(w[2][u*4+0], hv.x, p2); p2 = fmaf(w[2][u*4+1], hv.y, p2);
      p2 = fmaf(w[2][u*4+2], hv.z, p2); p2 = fmaf(w[2][u*4+3], hv.w, p2);
      p3 = fmaf(w[3][u*4+0], hv.x, p3); p3 = fmaf(w[3][u*4+1], hv.y, p3);
      p3 = fmaf(w[3][u*4+2], hv.z, p3); p3 = fmaf(w[3][u*4+3], hv.w, p3);
    }
    p0 = dpp_add<0xB1>(p0); p0 = dpp_add<0x4E>(p0);
    p1 = dpp_add<0xB1>(p1); p1 = dpp_add<0x4E>(p1);
    p2 = dpp_add<0xB1>(p2); p2 = dpp_add<0x4E>(p2);
    p3 = dpp_add<0xB1>(p3); p3 = dpp_add<0x4E>(p3);

    float gi = p0 + xg_cur[0], gf = p1 + xg_cur[1];
    float gc = p2 + xg_cur[2], go = p3 + xg_cur[3];
    float si = sigm(gi), sf = sigm(gf), so = sigm(go);
    c = fmaf(sf, c, si * tanh_f(gc));
    float h = so * tanh_f(c);

    if (q == 0) {
      hn[j] = h;
      houtb[(size_t)s * BB * HH + j] = h + res_cur;
      if (s == CH - 1) hst[j] = h;   // raw h for next chunk's state
    }
    #pragma unroll
    for (int g = 0; g < 4; g++) xg_cur[g] = xg_nxt[g];
    res_cur = res_nxt;
    __syncthreads();
    const float* tmp = hc; hc = hn; hn = (float*)tmp;
  }
  if (q == 0) cst[j] = c;
}

__global__ __launch_bounds__(256) void k_out(const float* __restrict__ x,
                                             const float* __restrict__ hfin,
                                             const float* __restrict__ cfin,
                                             void* __restrict__ out,
                                             const unsigned* __restrict__ flag) {
  int isbf = (int)*flag;
  int i = blockIdx.x * 256 + threadIdx.x;
  float v;
  if (i < TBH) v = x[i];
  else if (i < TBH + BH) v = hfin[i - TBH];
  else v = cfin[i - TBH - BH];
  if (isbf) ((__hip_bfloat16*)out)[i] = __float2bfloat16(v);
  else ((float*)out)[i] = v;
}

extern "C" void kernel_launch(void* const* d_in, const int* in_sizes, int n_in,
                              void* d_out, int out_size, void* d_ws, size_t ws_size,
                              hipStream_t stream) {
  const int* idx = (const int*)d_in[0];
  const void* emb   = d_in[1];
  const void* w_ih0 = d_in[2];
  const void* w_hh0 = d_in[3];
  const void* b0    = d_in[4];
  const void* w_ih1 = d_in[5];
  const void* w_hh1 = d_in[6];
  const void* b1    = d_in[7];
  const void* w_ihr = d_in[8];
  const void* w_hhr = d_in[9];
  const void* br    = d_in[10];

  float* ws   = (float*)d_ws;
  float* x0   = ws;                       // TBH   (L0 input; later: out7 full buffer)
  float* xcat = ws + TBH;                 // 2*TBH (L0 output / L1 input)
  float* xg_f = ws + 3 * (size_t)TBH;     // TBG   (L0 fwd xg; later: xg slots 0..7)
  float* hfin = ws + 3 * (size_t)TBH + TBG;        // 2*BH
  float* cfin = hfin + 2 * BH;                     // 2*BH
  unsigned* flag = (unsigned*)(cfin + 2 * BH);
  float* xg_b = cfin + 2 * BH + 16384;    // TBG (L0 bwd xg; later: slots 8..9 + rings + states)
  int merged = ws_size >= (size_t)(3 * (size_t)TBH + 2 * (size_t)TBG + 4 * BH + 16384 + 64) * 4;

  k_detect<<<1, 256, 0, stream>>>((const unsigned*)emb, flag);
  k_embed<<<TBH / 256, 256, 0, stream>>>(idx, emb, flag, x0);

  dim3 pg(512, 8);
  if (merged) {
    // ---- layer 0 (bidirectional), as before ----
    k_proj<<<pg, 256, 0, stream>>>(x0, w_ih0, 0, b0, 0, xg_f, HH, flag);
    k_proj<<<pg, 256, 0, stream>>>(x0, w_ih0, (size_t)GG * HH, b0, GG, xg_b, HH, flag);
    k_recur<<<128, 512, 0, stream>>>(xg_f, (size_t)(xg_b - xg_f), w_hh0, 0, (size_t)GG * HH,
                                     xcat, 2 * HH, HH, nullptr, hfin, cfin, 1, flag);

    // ---- layers 1..7: chunked wavefront, proj/recur as concurrent blocks ----
    // proj(r,k) at wave 2r-2+k ; recur(r,k) at wave 2r-1+k ; waves 0..20.
    float* outring = xg_b + 2 * (size_t)CHGG;
    float* hstate  = outring + 18 * (size_t)CHH;
    float* cstate  = hstate + 7 * (size_t)BH;
    for (int wv = 0; wv <= 2 * 7 - 1 + (NCH - 1); wv++) {
      WaveDesc wd; wd.n = 0;
      // recur cells first (critical path; launched first)
      for (int r = 1; r <= 7; r++) {
        int kk = wv - (2 * r - 1);
        if (kk >= 0 && kk < NCH) { wd.r[wd.n] = r; wd.k[wd.n] = kk; wd.role[wd.n] = 0; wd.n++; }
      }
      for (int r = 1; r <= 7; r++) {
        int kk = wv - (2 * r - 2);
        if (kk >= 0 && kk < NCH) { wd.r[wd.n] = r; wd.k[wd.n] = kk; wd.role[wd.n] = 1; wd.n++; }
      }
      if (wd.n)
        k_wave<<<wd.n * 64, 512, 0, stream>>>(wd, xg_f, xg_b, xcat, x0,
                                              w_ih1, w_hh1, b1, w_ihr, w_hhr, br, flag);
    }
    k_out<<<(TBH + 2 * BH) / 256, 256, 0, stream>>>(x0, hstate + 6 * BH, cstate + 6 * BH,
                                                    d_out, flag);
  } else {
    // ---- fallback: original fully-serial path ----
    k_proj<<<pg, 256, 0, stream>>>(x0, w_ih0, 0, b0, 0, xg_f, HH, flag);
    k_recur<<<64, 512, 0, stream>>>(xg_f, 0, w_hh0, 0, 0,
                                    xcat, 2 * HH, 0, nullptr, hfin, cfin, 0, flag);
    k_proj<<<pg, 256, 0, stream>>>(x0, w_ih0, (size_t)GG * HH, b0, GG, xg_f, HH, flag);
    k_recur<<<64, 512, 0, stream>>>(xg_f, 0, w_hh0, (size_t)GG * HH, 0,
                                    xcat + HH, 2 * HH, 0, nullptr, hfin, cfin, 2, flag);
    float* xA = xcat;
    float* xB = xcat + TBH;
    k_proj<<<pg, 256, 0, stream>>>(xcat, w_ih1, 0, b1, 0, xg_f, 2 * HH, flag);
    k_recur<<<64, 512, 0, stream>>>(xg_f, 0, w_hh1, 0, 0, xA, HH, 0, nullptr, hfin, cfin, 0, flag);
    float* cur = xA;
    float* nxt = xB;
    for (int r = 0; r < 6; r++) {
      k_proj<<<pg, 256, 0, stream>>>(cur, w_ihr, (size_t)r * GG * HH, br, (size_t)r * GG, xg_f, HH, flag);
      k_recur<<<64, 512, 0, stream>>>(xg_f, 0, w_hhr, (size_t)r * GG * HH, 0,
                                      nxt, HH, 0, cur, hfin, cfin, 0, flag);
      float* t = cur; cur = nxt; nxt = t;
    }
    k_out<<<(TBH + 2 * BH) / 256, 256, 0, stream>>>(cur, hfin, cfin, d_out, flag);
  }
}